// Round 3
// baseline (2494.856 us; speedup 1.0000x reference)
//
#include <hip/hip_runtime.h>

#define VN 6890
#define MP 6912            // padded M: 54*128, keeps A_T rows 16B-aligned
#define TN 100
#define NOUT 800           // 8 rotations * 100 templates

// ---------------------------------------------------------------------------
// x0[v,c] = (signal[v,c] - mean[c]) / sqrt(var[c])
__global__ __launch_bounds__(256) void norm_kernel(
    const float* __restrict__ sig, const float* __restrict__ mean,
    const float* __restrict__ var, float* __restrict__ x0)
{
    int i = blockIdx.x * blockDim.x + threadIdx.x;
    if (i < VN * 3) {
        int c = i % 3;
        x0[i] = (sig[i] - mean[c]) / sqrtf(var[c]);
    }
}

// ---------------------------------------------------------------------------
// Brot[k][n] = W[t, r, (a+rot)&7, c],  k = (r*8+a)*CIN + c,  n = rot*100 + t
template<int CIN>
__global__ __launch_bounds__(256) void rotw_kernel(
    const float* __restrict__ W, float* __restrict__ Brot)
{
    int k = blockIdx.x;
    int ra = k / CIN, c = k - ra * CIN;
    int r = ra >> 3, a = ra & 7;
    for (int n = threadIdx.x; n < NOUT; n += 256) {
        int rot = n / TN, t = n - rot * TN;
        int a2 = (a + rot) & 7;
        Brot[(size_t)k * NOUT + n] = W[((t * 5 + r) * 8 + a2) * CIN + c];
    }
}

// ---------------------------------------------------------------------------
// Transposed patch, CIN=3: PT[k][v] with k = ra*3+c, row stride MP.
__global__ __launch_bounds__(256) void patchT3(
    const float* __restrict__ x, const int* __restrict__ bidx,
    const float* __restrict__ bw, float* __restrict__ PT)
{
    int v = blockIdx.x * 256 + threadIdx.x;
    if (v >= VN) return;
    for (int ra = 0; ra < 40; ++ra) {
        int o = (v * 40 + ra) * 3;
        int i0 = bidx[o] * 3, i1 = bidx[o + 1] * 3, i2 = bidx[o + 2] * 3;
        float w0 = bw[o], w1 = bw[o + 1], w2 = bw[o + 2];
        #pragma unroll
        for (int c = 0; c < 3; ++c)
            PT[(size_t)(ra * 3 + c) * MP + v] =
                w0 * x[i0 + c] + w1 * x[i1 + c] + w2 * x[i2 + c];
    }
}

// ---------------------------------------------------------------------------
// Transposed patch, CIN=100: PT[k][v], k = ra*100+c. Writes coalesced over v,
// gathers x rows as float4 over c. grid (ceil(V/256), 40).
__global__ __launch_bounds__(256) void patchT100(
    const float* __restrict__ x, const int* __restrict__ bidx,
    const float* __restrict__ bw, float* __restrict__ PT)
{
    int v = blockIdx.x * 256 + threadIdx.x;
    int ra = blockIdx.y;
    if (v >= VN) return;
    int o = (v * 40 + ra) * 3;
    int i0 = bidx[o] * 100, i1 = bidx[o + 1] * 100, i2 = bidx[o + 2] * 100;
    float w0 = bw[o], w1 = bw[o + 1], w2 = bw[o + 2];
    size_t base = (size_t)(ra * 100) * MP + v;
    for (int c = 0; c < 100; c += 4) {
        float4 a = *reinterpret_cast<const float4*>(x + i0 + c);
        float4 b = *reinterpret_cast<const float4*>(x + i1 + c);
        float4 d = *reinterpret_cast<const float4*>(x + i2 + c);
        PT[base + (size_t)(c + 0) * MP] = w0 * a.x + w1 * b.x + w2 * d.x;
        PT[base + (size_t)(c + 1) * MP] = w0 * a.y + w1 * b.y + w2 * d.y;
        PT[base + (size_t)(c + 2) * MP] = w0 * a.z + w1 * b.z + w2 * d.z;
        PT[base + (size_t)(c + 3) * MP] = w0 * a.w + w1 * b.w + w2 * d.w;
    }
}

// ---------------------------------------------------------------------------
// Scalar-operand SGEMM, no LDS. Lanes = N dim (coalesced B loads / C stores),
// A side fetched via wave-uniform scalar loads (SMEM pipe, free vs VALU).
// Wave: 16 m-rows x 64 n-cols (acc[16]); block: 4 waves stacked over m (64 m).
// CONV: A = AT (K x MP) k-major -> merged s_load_dwordx16; bias[n%100] + relu.
// else: A row-major (M x K) -> 16 strided s_load_dword (sL1 hits across k);
//       bias[n], no relu.
template<bool CONV>
__global__ __launch_bounds__(256, 6) void gemm_sb(
    const float* __restrict__ A, const float* __restrict__ B,
    const float* __restrict__ bias, float* __restrict__ C,
    int N, int K)
{
    const int lane = threadIdx.x & 63;
    const int wv = __builtin_amdgcn_readfirstlane((int)(threadIdx.x >> 6));
    const int m0 = blockIdx.x * 64 + wv * 16;
    const int n  = blockIdx.y * 64 + lane;
    const int nc = n < N ? n : N - 1;          // clamp loads; stores masked
    const float* Bp = B + nc;
    const float* Ap = CONV ? (A + m0) : (A + (size_t)m0 * K);

    float acc[16];
    #pragma unroll
    for (int j = 0; j < 16; ++j) acc[j] = 0.f;

    #pragma unroll 2
    for (int k = 0; k < K; ++k) {
        float b = Bp[(size_t)k * N];           // coalesced vector load
        #pragma unroll
        for (int j = 0; j < 16; ++j) {
            float a = CONV ? Ap[(size_t)k * MP + j]   // uniform -> s_load x16
                           : Ap[(size_t)j * K + k];   // uniform -> s_load
            acc[j] = fmaf(a, b, acc[j]);
        }
    }

    if (n < N) {
        float bv = CONV ? bias[n % TN] : bias[n];
        #pragma unroll
        for (int j = 0; j < 16; ++j) {
            int m = m0 + j;
            if (m < VN) {
                float o = acc[j] + bv;
                if (CONV) o = fmaxf(o, 0.f);
                C[(size_t)m * N + n] = o;      // coalesced store
            }
        }
    }
}

// ---------------------------------------------------------------------------
// AngularMaxPooling + BatchNorm. One wave per vertex.
__global__ __launch_bounds__(256) void amp_bn(
    const float* __restrict__ conv,   // (VN, 800) layout [v][rot][t]
    const float* __restrict__ g,  const float* __restrict__ be,
    const float* __restrict__ mu, const float* __restrict__ var,
    float* __restrict__ xout)         // (VN, 100) row-major
{
    int v = blockIdx.x * 4 + (threadIdx.x >> 6);
    int lane = threadIdx.x & 63;
    if (v >= VN) return;
    const float* y = conv + (size_t)v * NOUT;

    float s[8];
    #pragma unroll
    for (int nq = 0; nq < 8; ++nq) {
        float t1 = y[nq * TN + lane];
        float t2 = (lane < 36) ? y[nq * TN + 64 + lane] : 0.f;
        s[nq] = t1 * t1 + t2 * t2;
    }
    #pragma unroll
    for (int off = 32; off > 0; off >>= 1)
        #pragma unroll
        for (int nq = 0; nq < 8; ++nq) s[nq] += __shfl_xor(s[nq], off);

    int best = 0; float bs = s[0];
    #pragma unroll
    for (int nq = 1; nq < 8; ++nq) { if (s[nq] > bs) { bs = s[nq]; best = nq; } }

    const float* yb = y + best * TN;
    for (int t = lane; t < TN; t += 64) {
        float inv = 1.0f / sqrtf(var[t] + 1e-3f);
        xout[v * TN + t] = g[t] * (yb[t] - mu[t]) * inv + be[t];
    }
}

// ---------------------------------------------------------------------------
extern "C" void kernel_launch(void* const* d_in, const int* in_sizes, int n_in,
                              void* d_out, int out_size, void* d_ws, size_t ws_size,
                              hipStream_t stream) {
    const float* signal = (const float*)d_in[0];
    const int*   bcix   = (const int*)  d_in[1];
    const float* bcw    = (const float*)d_in[2];
    const float* nmean  = (const float*)d_in[3];
    const float* nvar   = (const float*)d_in[4];
    const float* w0     = (const float*)d_in[5];
    const float* b0     = (const float*)d_in[6];
    const float* w1     = (const float*)d_in[7];
    const float* b1     = (const float*)d_in[8];
    const float* w2     = (const float*)d_in[9];
    const float* b2     = (const float*)d_in[10];
    const float* bng    = (const float*)d_in[11];
    const float* bnb    = (const float*)d_in[12];
    const float* bnm    = (const float*)d_in[13];
    const float* bnv    = (const float*)d_in[14];
    const float* dw     = (const float*)d_in[15];
    const float* db     = (const float*)d_in[16];
    float* out = (float*)d_out;

    // Small activations in ws (<= round-1's proven footprint).
    float* x0 = (float*)d_ws;
    float* xA = x0 + 20736;       // V*3 padded
    float* xB = xA + 689024;      // V*100 padded

    // Big scratch in d_out (47.47M floats), all dead before dense writes C:
    float* PT   = out;                       // 4000*6912 = 27,648,000
    float* conv = out + 27648000;            // 6890*800  =  5,512,000
    float* Brot = out + 27648000 + 5512000;  // 4000*800 (+slack) -> < 36.4M

    dim3 cgrid(108, 13);                     // (6890/64, 832/64)
    dim3 dgrid(108, 108);                    // dense: N=6890
    dim3 pgrid(27, 40);                      // patchT100
    int ampg = (VN + 3) / 4;

    norm_kernel<<<(VN * 3 + 255) / 256, 256, 0, stream>>>(signal, nmean, nvar, x0);

    // layer 0 (CIN=3, K=120)
    rotw_kernel<3><<<120, 256, 0, stream>>>(w0, Brot);
    patchT3<<<27, 256, 0, stream>>>(x0, bcix, bcw, PT);
    gemm_sb<true><<<cgrid, 256, 0, stream>>>(PT, Brot, b0, conv, NOUT, 120);
    amp_bn<<<ampg, 256, 0, stream>>>(conv, bng, bnb, bnm, bnv, xA);

    // layer 1 (CIN=100, K=4000)
    rotw_kernel<100><<<4000, 256, 0, stream>>>(w1, Brot);
    patchT100<<<pgrid, 256, 0, stream>>>(xA, bcix, bcw, PT);
    gemm_sb<true><<<cgrid, 256, 0, stream>>>(PT, Brot, b1, conv, NOUT, 4000);
    amp_bn<<<ampg, 256, 0, stream>>>(conv, bng + 100, bnb + 100, bnm + 100, bnv + 100, xB);

    // layer 2 (CIN=100, K=4000)
    rotw_kernel<100><<<4000, 256, 0, stream>>>(w2, Brot);
    patchT100<<<pgrid, 256, 0, stream>>>(xB, bcix, bcw, PT);
    gemm_sb<true><<<cgrid, 256, 0, stream>>>(PT, Brot, b2, conv, NOUT, 4000);
    amp_bn<<<ampg, 256, 0, stream>>>(conv, bng + 200, bnb + 200, bnm + 200, bnv + 200, xA);

    // dense head: out = xA(V x 100) @ dw(100 x V) + db
    gemm_sb<false><<<dgrid, 256, 0, stream>>>(xA, dw, db, out, VN, 100);
}